// Round 10
// baseline (5524.863 us; speedup 1.0000x reference)
//
#include <hip/hip_runtime.h>
#include <hip/hip_bf16.h>

#define SEQ   4096
#define DIM   768
#define HEADS 12
#define NQKV  2304
// Q pre-scaled by 0.125*log2(e) in QKV epilogue -> p = 2^st = exp(score/8)
#define QSCALE 0.18033688011f

#if __has_builtin(__builtin_amdgcn_exp2f)
#define EXP2(x) __builtin_amdgcn_exp2f(x)
#else
#define EXP2(x) __expf((x) * 0.69314718056f)
#endif

typedef __bf16 bf16_t;
typedef bf16_t bf16x8 __attribute__((ext_vector_type(8)));
typedef float  f32x4  __attribute__((ext_vector_type(4)));
typedef float  f32x16 __attribute__((ext_vector_type(16)));
typedef unsigned short u16;
typedef unsigned int   u32;

static __device__ __forceinline__ float bf2f(u16 v) {
    union { float f; unsigned u; } x; x.u = ((unsigned)v) << 16; return x.f;
}
static __device__ __forceinline__ u16 f2bf(float f) {
    union { float f; unsigned u; } x; x.f = f;
    unsigned r = x.u + 0x7fff + ((x.u >> 16) & 1);   // RNE
    return (u16)(r >> 16);
}
static __device__ __forceinline__ u32 fbits(float f) {
    union { float f; unsigned u; } x; x.f = f; return x.u;
}
static __device__ __forceinline__ void gload_lds16(const u16* g, u16* l) {
    __builtin_amdgcn_global_load_lds(
        (const __attribute__((address_space(1))) unsigned int*)g,
        (__attribute__((address_space(3))) unsigned int*)l, 16, 0, 0);
}

// per-block dtype self-detection (x fp32 vs bf16)
static __device__ __forceinline__ int detect_f32(const u32* __restrict__ x) {
    int lane = threadIdx.x & 63;
    int cnt = 0;
#pragma unroll
    for (int i = 0; i < 8; ++i) {
        u32 w = x[lane * 8 + i];
        cnt += (((w >> 7) & 0xFF) >= 0x8F) ? 1 : 0;
    }
#pragma unroll
    for (int m = 1; m < 64; m <<= 1) cnt += __shfl_xor(cnt, m);
    return cnt >= 64;
}

// ---- fused prep: [0,432) transpose w_qkv; [432,576) transpose w_proj; rest convert x+biases
__global__ __launch_bounds__(256) void prep(
    const void* __restrict__ x, const void* __restrict__ wqkv,
    const void* __restrict__ bqkv, const void* __restrict__ wproj,
    const void* __restrict__ bproj,
    u16* __restrict__ cvt, u16* __restrict__ wqkvT, u16* __restrict__ wprojT)
{
    __shared__ u16 tile[64][65];
    const bool f32 = detect_f32((const u32*)x) != 0;
    const int b = blockIdx.x;
    const int t = threadIdx.x;

    if (b < 576) {
        const void* src; u16* dst; int K, N, tx, ty;
        if (b < 432) { src = wqkv; dst = wqkvT; K = DIM; N = NQKV; tx = b % 36; ty = b / 36; }
        else { int bb = b - 432; src = wproj; dst = wprojT; K = DIM; N = DIM; tx = bb % 12; ty = bb / 12; }
        const int k0 = ty * 64, n0 = tx * 64;
#pragma unroll
        for (int i = 0; i < 16; ++i) {
            int idx = i * 256 + t;
            int r = idx >> 6, c = idx & 63;
            size_t si = (size_t)(k0 + r) * N + n0 + c;
            tile[r][c] = f32 ? f2bf(((const float*)src)[si]) : ((const u16*)src)[si];
        }
        __syncthreads();
#pragma unroll
        for (int i = 0; i < 16; ++i) {
            int idx = i * 256 + t;
            int r = idx >> 6, c = idx & 63;
            dst[(size_t)(n0 + r) * K + k0 + c] = tile[c][r];
        }
    } else {
        const int SX = SEQ * DIM, e1 = SX + NQKV;
        const int n_cvt = e1 + DIM;
        for (int i = (b - 576) * 256 + t; i < n_cvt; i += 200 * 256) {
            const void* s; int off;
            if      (i < SX) { s = x; off = i; }
            else if (i < e1) { s = bqkv; off = i - SX; }
            else             { s = bproj; off = i - e1; }
            cvt[i] = f32 ? f2bf(((const float*)s)[off]) : ((const u16*)s)[off];
        }
    }
}

// ---- m97-style GEMM (QKV): C[M,N] = A[M,K] @ BT[N,K]^T + bias[N]
// n<768 (Q) -> scaled by QSCALE; n<1536 (K) plain; n>=1536 (V) ->
// VT[(n-1536)*SEQ + mp], mp = key with bits2,3 swapped per 16-group.
__global__ __launch_bounds__(256) void gemm_qkv(
    const u16* __restrict__ A, const u16* __restrict__ BT, const u16* __restrict__ bias,
    u16* __restrict__ C0, u16* __restrict__ VT, int M, int N, int K)
{
    __shared__ u16 a_lds[128 * 32];
    __shared__ u16 b_lds[128 * 32];

    const int t    = threadIdx.x;
    const int w    = t >> 6;
    const int lane = t & 63;
    const int l15  = lane & 15;
    const int quad = lane >> 4;
    const int wm   = w >> 1, wn = w & 1;
    const int m0   = blockIdx.y * 128, n0 = blockIdx.x * 128;

    const int srow = w * 32 + (lane >> 2);
    const int kch  = (lane & 3) * 8;
    const u16* asrc = A  + (size_t)(m0 + srow) * K + kch;
    const u16* bsrc = BT + (size_t)(n0 + srow) * K + kch;
    u16* adst = a_lds + w * 32 * 32;
    u16* bdst = b_lds + w * 32 * 32;

    f32x4 acc[4][4] = {};

    for (int kt = 0; kt < K; kt += 32) {
        __syncthreads();
        gload_lds16(asrc,          adst);
        gload_lds16(asrc + 16 * K, adst + 16 * 32);
        gload_lds16(bsrc,          bdst);
        gload_lds16(bsrc + 16 * K, bdst + 16 * 32);
        asrc += 32; bsrc += 32;
        __syncthreads();

        const u16* ab = a_lds + (wm * 64 + l15) * 32 + quad * 8;
        const u16* bb = b_lds + (wn * 64 + l15) * 32 + quad * 8;
        bf16x8 af[4], bfr[4];
#pragma unroll
        for (int i = 0; i < 4; ++i) af[i]  = *(const bf16x8*)(ab + i * 16 * 32);
#pragma unroll
        for (int j = 0; j < 4; ++j) bfr[j] = *(const bf16x8*)(bb + j * 16 * 32);
#pragma unroll
        for (int i = 0; i < 4; ++i)
#pragma unroll
            for (int j = 0; j < 4; ++j)
                acc[i][j] = __builtin_amdgcn_mfma_f32_16x16x32_bf16(af[i], bfr[j], acc[i][j], 0, 0, 0);
    }

#pragma unroll
    for (int i = 0; i < 4; ++i)
#pragma unroll
        for (int j = 0; j < 4; ++j)
#pragma unroll
            for (int r = 0; r < 4; ++r) {
                int m = m0 + wm * 64 + i * 16 + quad * 4 + r;
                int n = n0 + wn * 64 + j * 16 + l15;
                float v = acc[i][j][r] + bf2f(bias[n]);
                if (n < 768) {
                    C0[(size_t)m * 1536 + n] = f2bf(v * QSCALE);
                } else if (n < 1536) {
                    C0[(size_t)m * 1536 + n] = f2bf(v);
                } else {
                    int mp = (m & ~15) | (m & 3) |
                             (((m >> 2) & 1) << 3) | (((m >> 3) & 1) << 2);
                    VT[(size_t)(n - 1536) * SEQ + mp] = f2bf(v);
                }
            }
}

// ---- proj GEMM, 64x128 tile (384 blocks for 4096x768): 4 waves = (wm 32-row) x (wn 64-col)
__global__ __launch_bounds__(256) void gemm_proj(
    const u16* __restrict__ A, const u16* __restrict__ BT, const u16* __restrict__ bias,
    u16* __restrict__ C0, float* __restrict__ Cf, const u32* __restrict__ xdet,
    int M, int N, int K)
{
    __shared__ u16 a_lds[64 * 32];
    __shared__ u16 b_lds[128 * 32];

    const int t    = threadIdx.x;
    const int w    = t >> 6;
    const int lane = t & 63;
    const int l15  = lane & 15;
    const int quad = lane >> 4;
    const int wm   = w & 1, wn = w >> 1;
    const int m0   = blockIdx.y * 64, n0 = blockIdx.x * 128;

    const int kch   = (lane & 3) * 8;
    const int srowA = w * 16 + (lane >> 2);
    const int srowB = w * 32 + (lane >> 2);
    const u16* asrc = A  + (size_t)(m0 + srowA) * K + kch;
    const u16* bsrc = BT + (size_t)(n0 + srowB) * K + kch;
    u16* adst = a_lds + w * 16 * 32;
    u16* bdst = b_lds + w * 32 * 32;

    f32x4 acc[2][4] = {};

    for (int kt = 0; kt < K; kt += 32) {
        __syncthreads();
        gload_lds16(asrc,          adst);
        gload_lds16(bsrc,          bdst);
        gload_lds16(bsrc + 16 * K, bdst + 16 * 32);
        asrc += 32; bsrc += 32;
        __syncthreads();

        const u16* ab = a_lds + (wm * 32 + l15) * 32 + quad * 8;
        const u16* bb = b_lds + (wn * 64 + l15) * 32 + quad * 8;
        bf16x8 af[2], bfr[4];
#pragma unroll
        for (int i = 0; i < 2; ++i) af[i]  = *(const bf16x8*)(ab + i * 16 * 32);
#pragma unroll
        for (int j = 0; j < 4; ++j) bfr[j] = *(const bf16x8*)(bb + j * 16 * 32);
#pragma unroll
        for (int i = 0; i < 2; ++i)
#pragma unroll
            for (int j = 0; j < 4; ++j)
                acc[i][j] = __builtin_amdgcn_mfma_f32_16x16x32_bf16(af[i], bfr[j], acc[i][j], 0, 0, 0);
    }

    const bool outf32 = detect_f32(xdet) != 0;
#pragma unroll
    for (int i = 0; i < 2; ++i)
#pragma unroll
        for (int j = 0; j < 4; ++j)
#pragma unroll
            for (int r = 0; r < 4; ++r) {
                int m = m0 + wm * 32 + i * 16 + quad * 4 + r;
                int n = n0 + wn * 64 + j * 16 + l15;
                float v = acc[i][j][r] + bf2f(bias[n]);
                if (outf32) Cf[(size_t)m * N + n] = v;
                else        C0[(size_t)m * N + n] = f2bf(v);
            }
}

// ---- Flash attention, BARRIER-FREE K-loop: K/V fragments loaded directly
// global->VGPR (no LDS, no __syncthreads, no vmcnt(0) drain — partial waits only).
// Block = (64 q, head); 4 waves = (q-half wq) x (key-half wk), each fully
// independent until the final reduce. S^T = K x Q^T; sigma-permuted V^T makes
// S^T C-regs directly the PV A-fragment. p = 2^st (Q pre-scaled by QSCALE).
// Row-sums via ones-MFMA on the same packed P. Register-double-buffered (1 tile ahead).
// Co-resident wq-pair waves share K/V lines via L1/L2.
__global__ __launch_bounds__(256, 3) void attn_kernel(
    const u16* __restrict__ qk, const u16* __restrict__ vt, u16* __restrict__ out)
{
    __shared__ float scr[2][32][64];    // 16 KB epilogue scratch
    __shared__ float l_red[2][2][32];   // [wq][wk][q]

    const int t    = threadIdx.x;
    const int w    = t >> 6;
    const int lane = t & 63;
    const int l31  = lane & 31;
    const int h    = lane >> 5;
    const int wq   = w & 1;
    const int wk   = w >> 1;
    const int head = blockIdx.y;
    const int q0   = blockIdx.x * 64 + wq * 32;

    // Q B-frags: q = q0+l31, d = h*8+16s+j
    const u16* qrow = qk + (size_t)(q0 + l31) * 1536 + head * 64 + h * 8;
    bf16x8 qb[4];
#pragma unroll
    for (int s = 0; s < 4; ++s) qb[s] = *(const bf16x8*)(qrow + 16 * s);

    bf16x8 ones;
#pragma unroll
    for (int j = 0; j < 8; ++j) ones[j] = (bf16_t)1.0f;

    const int krow = 32 * wk + l31;
    // K frag: row kt+krow, col 16s+8h (within head's 64-d block)
    const u16* kbase = qk + 768 + head * 64 + (size_t)krow * 1536 + h * 8;
    // V frag: rows d=l31 / 32+l31, col (4wk+2s2+h)*8 + kt
    const u16* vbase = vt + (size_t)head * 64 * SEQ + (size_t)l31 * SEQ + (4 * wk + h) * 8;

    f32x16 o0 = {}, o1 = {}, lac = {};

    bf16x8 ka[2][4], vb[2][2][2];   // [buf][s] / [buf][s2][half]

#define LOADT(buf, T)                                                          \
    {                                                                          \
        const u16* kp = kbase + (size_t)(T) * 64 * 1536;                       \
        const u16* vp = vbase + (T) * 64;                                      \
        ka[buf][0] = *(const bf16x8*)(kp);                                     \
        ka[buf][1] = *(const bf16x8*)(kp + 16);                                \
        ka[buf][2] = *(const bf16x8*)(kp + 32);                                \
        ka[buf][3] = *(const bf16x8*)(kp + 48);                                \
        vb[buf][0][0] = *(const bf16x8*)(vp);                                  \
        vb[buf][1][0] = *(const bf16x8*)(vp + 16);                             \
        vb[buf][0][1] = *(const bf16x8*)(vp + (size_t)32 * SEQ);               \
        vb[buf][1][1] = *(const bf16x8*)(vp + (size_t)32 * SEQ + 16);          \
    }

    LOADT(0, 0)
    for (int T = 0; T < 64; ++T) {
        const int cur = T & 1, nxt = cur ^ 1;
        if (T + 1 < 64) LOADT(nxt, T + 1)
        f32x16 st = {};
#pragma unroll
        for (int s = 0; s < 4; ++s)
            st = __builtin_amdgcn_mfma_f32_32x32x16_bf16(ka[cur][s], qb[s], st, 0, 0, 0);
        u32 q32[8];
#pragma unroll
        for (int i = 0; i < 8; ++i) {
            float pe = EXP2(st[2 * i]);
            float po = EXP2(st[2 * i + 1]);
            q32[i] = __builtin_amdgcn_perm(fbits(po), fbits(pe), 0x07060302u);
        }
        union { u32 u[4]; bf16x8 v; } pf0, pf1;
#pragma unroll
        for (int i = 0; i < 4; ++i) { pf0.u[i] = q32[i]; pf1.u[i] = q32[4 + i]; }
#pragma unroll
        for (int s2 = 0; s2 < 2; ++s2) {
            const bf16x8 pv = s2 ? pf1.v : pf0.v;
            o0  = __builtin_amdgcn_mfma_f32_32x32x16_bf16(pv, vb[cur][s2][0], o0, 0, 0, 0);
            o1  = __builtin_amdgcn_mfma_f32_32x32x16_bf16(pv, vb[cur][s2][1], o1, 0, 0, 0);
            lac = __builtin_amdgcn_mfma_f32_32x32x16_bf16(pv, ones, lac, 0, 0, 0);
        }
    }
#undef LOADT

    // publish l per q-row (lac is lane-uniform along cols)
    if (l31 == 0) {
#pragma unroll
        for (int r = 0; r < 16; ++r) {
            int row = (r & 3) + 8 * (r >> 2) + 4 * h;
            l_red[wq][wk][row] = lac[r];
        }
    }
    // O cross-wk reduce via LDS scratch
    if (wk == 1) {
#pragma unroll
        for (int r = 0; r < 16; ++r) {
            int row = (r & 3) + 8 * (r >> 2) + 4 * h;
            scr[wq][row][l31]      = o0[r];
            scr[wq][row][32 + l31] = o1[r];
        }
    }
    __syncthreads();
    if (wk == 0) {
#pragma unroll
        for (int r = 0; r < 16; ++r) {
            int row = (r & 3) + 8 * (r >> 2) + 4 * h;
            float lt   = l_red[wq][0][row] + l_red[wq][1][row];
            float invl = 1.0f / lt;
            float s0 = o0[r] + scr[wq][row][l31];
            float s1 = o1[r] + scr[wq][row][32 + l31];
            size_t gr = (size_t)(q0 + row) * 768 + head * 64;
            out[gr + l31]      = f2bf(s0 * invl);
            out[gr + 32 + l31] = f2bf(s1 * invl);
        }
    }
}

extern "C" void kernel_launch(void* const* d_in, const int* in_sizes, int n_in,
                              void* d_out, int out_size, void* d_ws, size_t ws_size,
                              hipStream_t stream) {
    const int SX = SEQ * DIM;

    u16* base   = (u16*)d_ws;
    u16* xb     = base;                               // [SEQ][DIM] bf16
    u16* bqkvb  = xb + SX;
    u16* bprojb = bqkvb + NQKV;
    u16* wqkvT  = bprojb + DIM;                       // [NQKV][DIM]
    u16* wprojT = wqkvT + (size_t)NQKV * DIM;         // [DIM][DIM]
    u16* qkb    = wprojT + (size_t)DIM * DIM;         // [SEQ][1536] Q(scaled)|K
    u16* vtb    = qkb + (size_t)SEQ * 1536;           // [H][64][SEQ] V^T (sigma keys)
    u16* attnb  = xb;                                 // reuse x region

    prep<<<776, 256, 0, stream>>>(
        d_in[0], d_in[1], d_in[2], d_in[3], d_in[4], base, wqkvT, wprojT);
    gemm_qkv<<<dim3(NQKV / 128, SEQ / 128), 256, 0, stream>>>(
        xb, wqkvT, bqkvb, qkb, vtb, SEQ, NQKV, DIM);
    attn_kernel<<<dim3(SEQ / 64, HEADS), 256, 0, stream>>>(qkb, vtb, attnb);
    gemm_proj<<<dim3(DIM / 128, SEQ / 64), 256, 0, stream>>>(
        attnb, wprojT, bprojb, (u16*)d_out, (float*)d_out, (const u32*)d_in[0],
        SEQ, DIM, DIM);
}

// Round 11
// 324.568 us; speedup vs baseline: 17.0222x; 17.0222x over previous
//
#include <hip/hip_runtime.h>
#include <hip/hip_bf16.h>

#define SEQ   4096
#define DIM   768
#define HEADS 12
#define NQKV  2304
// Q pre-scaled by 0.125*log2(e) in QKV epilogue -> p = 2^st = exp(score/8)
#define QSCALE 0.18033688011f

#if __has_builtin(__builtin_amdgcn_exp2f)
#define EXP2(x) __builtin_amdgcn_exp2f(x)
#else
#define EXP2(x) __expf((x) * 0.69314718056f)
#endif

typedef __bf16 bf16_t;
typedef bf16_t bf16x8 __attribute__((ext_vector_type(8)));
typedef float  f32x4  __attribute__((ext_vector_type(4)));
typedef float  f32x16 __attribute__((ext_vector_type(16)));
typedef unsigned short u16;
typedef unsigned int   u32;

static __device__ __forceinline__ float bf2f(u16 v) {
    union { float f; unsigned u; } x; x.u = ((unsigned)v) << 16; return x.f;
}
static __device__ __forceinline__ u16 f2bf(float f) {
    union { float f; unsigned u; } x; x.f = f;
    unsigned r = x.u + 0x7fff + ((x.u >> 16) & 1);   // RNE
    return (u16)(r >> 16);
}
static __device__ __forceinline__ u32 fbits(float f) {
    union { float f; unsigned u; } x; x.f = f; return x.u;
}
static __device__ __forceinline__ void gload_lds16(const u16* g, u16* l) {
    __builtin_amdgcn_global_load_lds(
        (const __attribute__((address_space(1))) unsigned int*)g,
        (__attribute__((address_space(3))) unsigned int*)l, 16, 0, 0);
}

// per-block dtype self-detection (x fp32 vs bf16)
static __device__ __forceinline__ int detect_f32(const u32* __restrict__ x) {
    int lane = threadIdx.x & 63;
    int cnt = 0;
#pragma unroll
    for (int i = 0; i < 8; ++i) {
        u32 w = x[lane * 8 + i];
        cnt += (((w >> 7) & 0xFF) >= 0x8F) ? 1 : 0;
    }
#pragma unroll
    for (int m = 1; m < 64; m <<= 1) cnt += __shfl_xor(cnt, m);
    return cnt >= 64;
}

// ---- fused prep: [0,432) transpose w_qkv; [432,576) transpose w_proj; rest convert x+biases
__global__ __launch_bounds__(256) void prep(
    const void* __restrict__ x, const void* __restrict__ wqkv,
    const void* __restrict__ bqkv, const void* __restrict__ wproj,
    const void* __restrict__ bproj,
    u16* __restrict__ cvt, u16* __restrict__ wqkvT, u16* __restrict__ wprojT)
{
    __shared__ u16 tile[64][65];
    const bool f32 = detect_f32((const u32*)x) != 0;
    const int b = blockIdx.x;
    const int t = threadIdx.x;

    if (b < 576) {
        const void* src; u16* dst; int K, N, tx, ty;
        if (b < 432) { src = wqkv; dst = wqkvT; K = DIM; N = NQKV; tx = b % 36; ty = b / 36; }
        else { int bb = b - 432; src = wproj; dst = wprojT; K = DIM; N = DIM; tx = bb % 12; ty = bb / 12; }
        const int k0 = ty * 64, n0 = tx * 64;
#pragma unroll
        for (int i = 0; i < 16; ++i) {
            int idx = i * 256 + t;
            int r = idx >> 6, c = idx & 63;
            size_t si = (size_t)(k0 + r) * N + n0 + c;
            tile[r][c] = f32 ? f2bf(((const float*)src)[si]) : ((const u16*)src)[si];
        }
        __syncthreads();
#pragma unroll
        for (int i = 0; i < 16; ++i) {
            int idx = i * 256 + t;
            int r = idx >> 6, c = idx & 63;
            dst[(size_t)(n0 + r) * K + k0 + c] = tile[c][r];
        }
    } else {
        const int SX = SEQ * DIM, e1 = SX + NQKV;
        const int n_cvt = e1 + DIM;
        for (int i = (b - 576) * 256 + t; i < n_cvt; i += 200 * 256) {
            const void* s; int off;
            if      (i < SX) { s = x; off = i; }
            else if (i < e1) { s = bqkv; off = i - SX; }
            else             { s = bproj; off = i - e1; }
            cvt[i] = f32 ? f2bf(((const float*)s)[off]) : ((const u16*)s)[off];
        }
    }
}

// ---- m97-style GEMM (QKV): C[M,N] = A[M,K] @ BT[N,K]^T + bias[N]
// n<768 (Q) -> scaled by QSCALE; n<1536 (K) plain; n>=1536 (V) ->
// VT[(n-1536)*SEQ + mp], mp = key with bits2,3 swapped per 16-group.
__global__ __launch_bounds__(256) void gemm_qkv(
    const u16* __restrict__ A, const u16* __restrict__ BT, const u16* __restrict__ bias,
    u16* __restrict__ C0, u16* __restrict__ VT, int M, int N, int K)
{
    __shared__ u16 a_lds[128 * 32];
    __shared__ u16 b_lds[128 * 32];

    const int t    = threadIdx.x;
    const int w    = t >> 6;
    const int lane = t & 63;
    const int l15  = lane & 15;
    const int quad = lane >> 4;
    const int wm   = w >> 1, wn = w & 1;
    const int m0   = blockIdx.y * 128, n0 = blockIdx.x * 128;

    const int srow = w * 32 + (lane >> 2);
    const int kch  = (lane & 3) * 8;
    const u16* asrc = A  + (size_t)(m0 + srow) * K + kch;
    const u16* bsrc = BT + (size_t)(n0 + srow) * K + kch;
    u16* adst = a_lds + w * 32 * 32;
    u16* bdst = b_lds + w * 32 * 32;

    f32x4 acc[4][4] = {};

    for (int kt = 0; kt < K; kt += 32) {
        __syncthreads();
        gload_lds16(asrc,          adst);
        gload_lds16(asrc + 16 * K, adst + 16 * 32);
        gload_lds16(bsrc,          bdst);
        gload_lds16(bsrc + 16 * K, bdst + 16 * 32);
        asrc += 32; bsrc += 32;
        __syncthreads();

        const u16* ab = a_lds + (wm * 64 + l15) * 32 + quad * 8;
        const u16* bb = b_lds + (wn * 64 + l15) * 32 + quad * 8;
        bf16x8 af[4], bfr[4];
#pragma unroll
        for (int i = 0; i < 4; ++i) af[i]  = *(const bf16x8*)(ab + i * 16 * 32);
#pragma unroll
        for (int j = 0; j < 4; ++j) bfr[j] = *(const bf16x8*)(bb + j * 16 * 32);
#pragma unroll
        for (int i = 0; i < 4; ++i)
#pragma unroll
            for (int j = 0; j < 4; ++j)
                acc[i][j] = __builtin_amdgcn_mfma_f32_16x16x32_bf16(af[i], bfr[j], acc[i][j], 0, 0, 0);
    }

#pragma unroll
    for (int i = 0; i < 4; ++i)
#pragma unroll
        for (int j = 0; j < 4; ++j)
#pragma unroll
            for (int r = 0; r < 4; ++r) {
                int m = m0 + wm * 64 + i * 16 + quad * 4 + r;
                int n = n0 + wn * 64 + j * 16 + l15;
                float v = acc[i][j][r] + bf2f(bias[n]);
                if (n < 768) {
                    C0[(size_t)m * 1536 + n] = f2bf(v * QSCALE);
                } else if (n < 1536) {
                    C0[(size_t)m * 1536 + n] = f2bf(v);
                } else {
                    int mp = (m & ~15) | (m & 3) |
                             (((m >> 2) & 1) << 3) | (((m >> 3) & 1) << 2);
                    VT[(size_t)(n - 1536) * SEQ + mp] = f2bf(v);
                }
            }
}

// ---- proj GEMM, 64x128 tile: 4 waves = (wm 32-row) x (wn 64-col)
__global__ __launch_bounds__(256) void gemm_proj(
    const u16* __restrict__ A, const u16* __restrict__ BT, const u16* __restrict__ bias,
    u16* __restrict__ C0, float* __restrict__ Cf, const u32* __restrict__ xdet,
    int M, int N, int K)
{
    __shared__ u16 a_lds[64 * 32];
    __shared__ u16 b_lds[128 * 32];

    const int t    = threadIdx.x;
    const int w    = t >> 6;
    const int lane = t & 63;
    const int l15  = lane & 15;
    const int quad = lane >> 4;
    const int wm   = w & 1, wn = w >> 1;
    const int m0   = blockIdx.y * 64, n0 = blockIdx.x * 128;

    const int kch   = (lane & 3) * 8;
    const int srowA = w * 16 + (lane >> 2);
    const int srowB = w * 32 + (lane >> 2);
    const u16* asrc = A  + (size_t)(m0 + srowA) * K + kch;
    const u16* bsrc = BT + (size_t)(n0 + srowB) * K + kch;
    u16* adst = a_lds + w * 16 * 32;
    u16* bdst = b_lds + w * 32 * 32;

    f32x4 acc[2][4] = {};

    for (int kt = 0; kt < K; kt += 32) {
        __syncthreads();
        gload_lds16(asrc,          adst);
        gload_lds16(bsrc,          bdst);
        gload_lds16(bsrc + 16 * K, bdst + 16 * 32);
        asrc += 32; bsrc += 32;
        __syncthreads();

        const u16* ab = a_lds + (wm * 32 + l15) * 32 + quad * 8;
        const u16* bb = b_lds + (wn * 64 + l15) * 32 + quad * 8;
        bf16x8 af[2], bfr[4];
#pragma unroll
        for (int i = 0; i < 2; ++i) af[i]  = *(const bf16x8*)(ab + i * 16 * 32);
#pragma unroll
        for (int j = 0; j < 4; ++j) bfr[j] = *(const bf16x8*)(bb + j * 16 * 32);
#pragma unroll
        for (int i = 0; i < 2; ++i)
#pragma unroll
            for (int j = 0; j < 4; ++j)
                acc[i][j] = __builtin_amdgcn_mfma_f32_16x16x32_bf16(af[i], bfr[j], acc[i][j], 0, 0, 0);
    }

    const bool outf32 = detect_f32(xdet) != 0;
#pragma unroll
    for (int i = 0; i < 2; ++i)
#pragma unroll
        for (int j = 0; j < 4; ++j)
#pragma unroll
            for (int r = 0; r < 4; ++r) {
                int m = m0 + wm * 32 + i * 16 + quad * 4 + r;
                int n = n0 + wn * 64 + j * 16 + l15;
                float v = acc[i][j][r] + bf2f(bias[n]);
                if (outf32) Cf[(size_t)m * N + n] = v;
                else        C0[(size_t)m * N + n] = f2bf(v);
            }
}

// ---- Flash attention, BARRIER-FREE K-loop, global->VGPR K/V fragments.
// COMPILE-TIME buffer indices (R10's runtime `cur` index sent the buffers to
// scratch: 662 MB spill traffic). All ka/vb subscripts below are literals.
__global__ __launch_bounds__(256, 3) void attn_kernel(
    const u16* __restrict__ qk, const u16* __restrict__ vt, u16* __restrict__ out)
{
    __shared__ float scr[2][32][64];    // 16 KB epilogue scratch
    __shared__ float l_red[2][2][32];   // [wq][wk][q]

    const int t    = threadIdx.x;
    const int w    = t >> 6;
    const int lane = t & 63;
    const int l31  = lane & 31;
    const int h    = lane >> 5;
    const int wq   = w & 1;
    const int wk   = w >> 1;
    const int head = blockIdx.y;
    const int q0   = blockIdx.x * 64 + wq * 32;

    // Q B-frags: q = q0+l31, d = h*8+16s+j
    const u16* qrow = qk + (size_t)(q0 + l31) * 1536 + head * 64 + h * 8;
    bf16x8 qb[4];
#pragma unroll
    for (int s = 0; s < 4; ++s) qb[s] = *(const bf16x8*)(qrow + 16 * s);

    bf16x8 ones;
#pragma unroll
    for (int j = 0; j < 8; ++j) ones[j] = (bf16_t)1.0f;

    const int krow = 32 * wk + l31;
    const u16* kbase = qk + 768 + head * 64 + (size_t)krow * 1536 + h * 8;
    const u16* vbase = vt + (size_t)head * 64 * SEQ + (size_t)l31 * SEQ + (4 * wk + h) * 8;

    f32x16 o0 = {}, o1 = {}, lac = {};

    bf16x8 ka0_0, ka0_1, ka0_2, ka0_3, vb0_00, vb0_10, vb0_01, vb0_11;
    bf16x8 ka1_0, ka1_1, ka1_2, ka1_3, vb1_00, vb1_10, vb1_01, vb1_11;

#define LOADT(B, T)                                                            \
    {                                                                          \
        const u16* kp = kbase + (size_t)(T) * 64 * 1536;                       \
        const u16* vp = vbase + (T) * 64;                                      \
        ka##B##_0 = *(const bf16x8*)(kp);                                      \
        ka##B##_1 = *(const bf16x8*)(kp + 16);                                 \
        ka##B##_2 = *(const bf16x8*)(kp + 32);                                 \
        ka##B##_3 = *(const bf16x8*)(kp + 48);                                 \
        vb##B##_00 = *(const bf16x8*)(vp);                                     \
        vb##B##_10 = *(const bf16x8*)(vp + 16);                                \
        vb##B##_01 = *(const bf16x8*)(vp + (size_t)32 * SEQ);                  \
        vb##B##_11 = *(const bf16x8*)(vp + (size_t)32 * SEQ + 16);             \
    }

#define COMPUTE(B)                                                             \
    {                                                                          \
        f32x16 st = {};                                                        \
        st = __builtin_amdgcn_mfma_f32_32x32x16_bf16(ka##B##_0, qb[0], st, 0, 0, 0); \
        st = __builtin_amdgcn_mfma_f32_32x32x16_bf16(ka##B##_1, qb[1], st, 0, 0, 0); \
        st = __builtin_amdgcn_mfma_f32_32x32x16_bf16(ka##B##_2, qb[2], st, 0, 0, 0); \
        st = __builtin_amdgcn_mfma_f32_32x32x16_bf16(ka##B##_3, qb[3], st, 0, 0, 0); \
        u32 q32[8];                                                            \
        _Pragma("unroll")                                                      \
        for (int i = 0; i < 8; ++i) {                                          \
            float pe = EXP2(st[2 * i]);                                        \
            float po = EXP2(st[2 * i + 1]);                                    \
            q32[i] = __builtin_amdgcn_perm(fbits(po), fbits(pe), 0x07060302u); \
        }                                                                      \
        union { u32 u[4]; bf16x8 v; } pf0, pf1;                                \
        _Pragma("unroll")                                                      \
        for (int i = 0; i < 4; ++i) { pf0.u[i] = q32[i]; pf1.u[i] = q32[4 + i]; } \
        o0  = __builtin_amdgcn_mfma_f32_32x32x16_bf16(pf0.v, vb##B##_00, o0, 0, 0, 0); \
        o1  = __builtin_amdgcn_mfma_f32_32x32x16_bf16(pf0.v, vb##B##_01, o1, 0, 0, 0); \
        lac = __builtin_amdgcn_mfma_f32_32x32x16_bf16(pf0.v, ones, lac, 0, 0, 0); \
        o0  = __builtin_amdgcn_mfma_f32_32x32x16_bf16(pf1.v, vb##B##_10, o0, 0, 0, 0); \
        o1  = __builtin_amdgcn_mfma_f32_32x32x16_bf16(pf1.v, vb##B##_11, o1, 0, 0, 0); \
        lac = __builtin_amdgcn_mfma_f32_32x32x16_bf16(pf1.v, ones, lac, 0, 0, 0); \
    }

    LOADT(0, 0)
    for (int T = 0; T < 64; T += 2) {
        LOADT(1, T + 1)
        COMPUTE(0)
        if (T + 2 < 64) LOADT(0, T + 2)
        COMPUTE(1)
    }
#undef LOADT
#undef COMPUTE

    // publish l per q-row (lac is lane-uniform along cols)
    if (l31 == 0) {
#pragma unroll
        for (int r = 0; r < 16; ++r) {
            int row = (r & 3) + 8 * (r >> 2) + 4 * h;
            l_red[wq][wk][row] = lac[r];
        }
    }
    // O cross-wk reduce via LDS scratch
    if (wk == 1) {
#pragma unroll
        for (int r = 0; r < 16; ++r) {
            int row = (r & 3) + 8 * (r >> 2) + 4 * h;
            scr[wq][row][l31]      = o0[r];
            scr[wq][row][32 + l31] = o1[r];
        }
    }
    __syncthreads();
    if (wk == 0) {
#pragma unroll
        for (int r = 0; r < 16; ++r) {
            int row = (r & 3) + 8 * (r >> 2) + 4 * h;
            float lt   = l_red[wq][0][row] + l_red[wq][1][row];
            float invl = 1.0f / lt;
            float s0 = o0[r] + scr[wq][row][l31];
            float s1 = o1[r] + scr[wq][row][32 + l31];
            size_t gr = (size_t)(q0 + row) * 768 + head * 64;
            out[gr + l31]      = f2bf(s0 * invl);
            out[gr + 32 + l31] = f2bf(s1 * invl);
        }
    }
}

extern "C" void kernel_launch(void* const* d_in, const int* in_sizes, int n_in,
                              void* d_out, int out_size, void* d_ws, size_t ws_size,
                              hipStream_t stream) {
    const int SX = SEQ * DIM;

    u16* base   = (u16*)d_ws;
    u16* xb     = base;                               // [SEQ][DIM] bf16
    u16* bqkvb  = xb + SX;
    u16* bprojb = bqkvb + NQKV;
    u16* wqkvT  = bprojb + DIM;                       // [NQKV][DIM]
    u16* wprojT = wqkvT + (size_t)NQKV * DIM;         // [DIM][DIM]
    u16* qkb    = wprojT + (size_t)DIM * DIM;         // [SEQ][1536] Q(scaled)|K
    u16* vtb    = qkb + (size_t)SEQ * 1536;           // [H][64][SEQ] V^T (sigma keys)
    u16* attnb  = xb;                                 // reuse x region

    prep<<<776, 256, 0, stream>>>(
        d_in[0], d_in[1], d_in[2], d_in[3], d_in[4], base, wqkvT, wprojT);
    gemm_qkv<<<dim3(NQKV / 128, SEQ / 128), 256, 0, stream>>>(
        xb, wqkvT, bqkvb, qkb, vtb, SEQ, NQKV, DIM);
    attn_kernel<<<dim3(SEQ / 64, HEADS), 256, 0, stream>>>(qkb, vtb, attnb);
    gemm_proj<<<dim3(DIM / 128, SEQ / 64), 256, 0, stream>>>(
        attnb, wprojT, bprojb, (u16*)d_out, (float*)d_out, (const u32*)d_in[0],
        SEQ, DIM, DIM);
}